// Round 4
// baseline (91.221 us; speedup 1.0000x reference)
//
#include <hip/hip_runtime.h>

// Per-row vector quantization:
//   x: [4096, 2048] fp32, values: [4096, 16] fp32
//   out[r][c] = values[r][argmin_v (x[r][c] - values[r][v])^2]
//
// Exact-semantics strategy (absmax must be 0):
//  - d_i = fl(fl(x - v_i)^2), same rounding as numpy (packed v_pk_add/mul_f32
//    are IEEE-identical per half; no fma contraction in t*t).
//  - min via v_min3_f32 tree: finite non-NaN inputs -> md bit-equal to >=1 d_i.
//  - descending equality-overwrite (i = 14..0, bv seeded with v[15]) leaves
//    the LOWEST matching index = numpy argmin first-occurrence tie-break.
//    Seed is safe: at least one index matches md; if any i<15 matches it
//    overwrites the seed; if only i=15 matches, the seed is correct.

#define N_ROWS 4096
#define N_COLS 2048
#define N_VALS 16

typedef float f32x2 __attribute__((ext_vector_type(2)));
typedef float f32x4 __attribute__((ext_vector_type(4)));  // native vector: OK for nontemporal builtins

static __device__ __forceinline__ float min3f(float a, float b, float c) {
    return fminf(fminf(a, b), c);   // folds to v_min3_f32
}

__global__ __launch_bounds__(256) void vq_rowcodebook_kernel(
    const float* __restrict__ x,
    const float* __restrict__ values,
    float* __restrict__ out)
{
    const int row = blockIdx.x;

    // Wave-uniform codebook address -> scalar loads (s_load_dwordx16 broadcast).
    const float* vr = values + (size_t)row * N_VALS;
    float v[N_VALS];
#pragma unroll
    for (int i = 0; i < N_VALS; ++i) v[i] = vr[i];

    const f32x4* xr   = (const f32x4*)(x   + (size_t)row * N_COLS);
    f32x4*       outr = (f32x4*)      (out + (size_t)row * N_COLS);

    // 2048 cols = 512 float4; 256 threads -> 2 iterations, fully coalesced.
#pragma unroll
    for (int it = 0; it < 2; ++it) {
        const int j = threadIdx.x + it * 256;
        const f32x4 xv = __builtin_nontemporal_load(&xr[j]);

        f32x4 o;
#pragma unroll
        for (int e = 0; e < 4; ++e) {
            const float xe = xv[e];
            f32x2 xe2; xe2.x = xe; xe2.y = xe;

            // 16 distances as 8 packed float2 sub+mul (v_pk_add/v_pk_mul).
            float d[N_VALS];
#pragma unroll
            for (int i = 0; i < N_VALS / 2; ++i) {
                f32x2 vv; vv.x = v[2 * i]; vv.y = v[2 * i + 1];
                f32x2 t  = xe2 - vv;
                f32x2 sq = t * t;
                d[2 * i]     = sq.x;
                d[2 * i + 1] = sq.y;
            }

            // min3 tree: depth 4, 8 instructions.
            const float t0 = min3f(d[0],  d[1],  d[2]);
            const float t1 = min3f(d[3],  d[4],  d[5]);
            const float t2 = min3f(d[6],  d[7],  d[8]);
            const float t3 = min3f(d[9],  d[10], d[11]);
            const float t4 = min3f(d[12], d[13], d[14]);
            const float u0 = min3f(t0, t1, t2);
            const float u1 = min3f(t3, t4, d[15]);
            const float md = fminf(u0, u1);

            // Descending overwrite seeded with v[15]: lowest match wins.
            float bv = v[15];
#pragma unroll
            for (int i = N_VALS - 2; i >= 0; --i)
                bv = (d[i] == md) ? v[i] : bv;

            o[e] = bv;
        }
        __builtin_nontemporal_store(o, &outr[j]);
    }
}

extern "C" void kernel_launch(void* const* d_in, const int* in_sizes, int n_in,
                              void* d_out, int out_size, void* d_ws, size_t ws_size,
                              hipStream_t stream) {
    const float* x      = (const float*)d_in[0];
    const float* values = (const float*)d_in[1];
    float* out          = (float*)d_out;

    vq_rowcodebook_kernel<<<N_ROWS, 256, 0, stream>>>(x, values, out);
}

// Round 5
// 86.496 us; speedup vs baseline: 1.0546x; 1.0546x over previous
//
#include <hip/hip_runtime.h>

// Per-row vector quantization:
//   x: [4096, 2048] fp32, values: [4096, 16] fp32
//   out[r][c] = values[r][argmin_v (x[r][c] - values[r][v])^2]
//
// Exact-semantics strategy (absmax must be 0):
//  - d_i = fl(fl(x - v_i)^2), same rounding as numpy (packed v_pk_add/mul_f32
//    are IEEE-identical per half; no fma contraction in t*t).
//  - min via v_min3_f32 tree: finite non-NaN inputs -> md bit-equal to >=1 d_i.
//  - descending equality-overwrite (i = 14..0, bv seeded with v[15]) leaves
//    the LOWEST matching index = numpy argmin first-occurrence tie-break.
//    Seed is safe: at least one index matches md; if any i<15 matches it
//    overwrites the seed; if only i=15 matches, the seed is correct.
//
// R4 lesson: nontemporal load/store hints REGRESSED (86.8 -> 91.2 us) —
// nt's early-L2-evict hurts the store stream. Plain loads/stores here.

#define N_ROWS 4096
#define N_COLS 2048
#define N_VALS 16

typedef float f32x2 __attribute__((ext_vector_type(2)));
typedef float f32x4 __attribute__((ext_vector_type(4)));

static __device__ __forceinline__ float min3f(float a, float b, float c) {
    return fminf(fminf(a, b), c);   // folds to v_min3_f32
}

__global__ __launch_bounds__(256) void vq_rowcodebook_kernel(
    const float* __restrict__ x,
    const float* __restrict__ values,
    float* __restrict__ out)
{
    const int row = blockIdx.x;

    // Wave-uniform codebook address -> scalar loads (s_load_dwordx16 broadcast).
    const float* vr = values + (size_t)row * N_VALS;
    float v[N_VALS];
#pragma unroll
    for (int i = 0; i < N_VALS; ++i) v[i] = vr[i];

    const f32x4* xr   = (const f32x4*)(x   + (size_t)row * N_COLS);
    f32x4*       outr = (f32x4*)      (out + (size_t)row * N_COLS);

    // 2048 cols = 512 float4; 256 threads -> 2 iterations, fully coalesced.
#pragma unroll
    for (int it = 0; it < 2; ++it) {
        const int j = threadIdx.x + it * 256;
        const f32x4 xv = xr[j];

        f32x4 o;
#pragma unroll
        for (int e = 0; e < 4; ++e) {
            const float xe = xv[e];
            f32x2 xe2; xe2.x = xe; xe2.y = xe;

            // 16 distances as 8 packed float2 sub+mul (v_pk_add/v_pk_mul).
            float d[N_VALS];
#pragma unroll
            for (int i = 0; i < N_VALS / 2; ++i) {
                f32x2 vv; vv.x = v[2 * i]; vv.y = v[2 * i + 1];
                f32x2 t  = xe2 - vv;
                f32x2 sq = t * t;
                d[2 * i]     = sq.x;
                d[2 * i + 1] = sq.y;
            }

            // min3 tree: depth 4, 8 instructions.
            const float t0 = min3f(d[0],  d[1],  d[2]);
            const float t1 = min3f(d[3],  d[4],  d[5]);
            const float t2 = min3f(d[6],  d[7],  d[8]);
            const float t3 = min3f(d[9],  d[10], d[11]);
            const float t4 = min3f(d[12], d[13], d[14]);
            const float u0 = min3f(t0, t1, t2);
            const float u1 = min3f(t3, t4, d[15]);
            const float md = fminf(u0, u1);

            // Descending overwrite seeded with v[15]: lowest match wins.
            float bv = v[15];
#pragma unroll
            for (int i = N_VALS - 2; i >= 0; --i)
                bv = (d[i] == md) ? v[i] : bv;

            o[e] = bv;
        }
        outr[j] = o;
    }
}

extern "C" void kernel_launch(void* const* d_in, const int* in_sizes, int n_in,
                              void* d_out, int out_size, void* d_ws, size_t ws_size,
                              hipStream_t stream) {
    const float* x      = (const float*)d_in[0];
    const float* values = (const float*)d_in[1];
    float* out          = (float*)d_out;

    vq_rowcodebook_kernel<<<N_ROWS, 256, 0, stream>>>(x, values, out);
}

// Round 6
// 82.881 us; speedup vs baseline: 1.1006x; 1.0436x over previous
//
#include <hip/hip_runtime.h>
#include <math.h>

// Per-row VQ via per-block SORTED codebook + branchless binary search.
//   x: [4096, 2048] fp32, values: [4096, 16] fp32
//   out[r][c] = values[r][argmin_v fl(fl(x-v)^2)], first-index tie-break.
//
// Exactness: fl(t^2) is monotone in |t| => the argmin over all 16 rounded
// squares is attained at one of the two sorted neighbors of x (up to ties
// whose candidate VALUES differ by < ~3e-7 -- far below the 8.9e-2
// threshold). The only large-error tie (x near the midpoint of two distant
// values, squares round equal) is exactly the L-vs-R tie, resolved here
// bit-exactly by comparing ORIGINAL indices (numpy argmin-first semantics).
//
// Issue-count model (measured 0.102 us per VALU issue/element):
//   old: 16 dist + 9 min-tree + 30 select = ~54/elem
//   new: ~14 search + 4 dist + 6 select  = ~25/elem  -> predict ~ -3 us.

#define N_ROWS 4096
#define N_COLS 2048
#define N_VALS 16

typedef float f32x4 __attribute__((ext_vector_type(4)));

struct Entry { float v; int idx; };   // 8 B, LDS: entry k at byte 8k

__global__ __launch_bounds__(256) void vq_rowcodebook_kernel(
    const float* __restrict__ x,
    const float* __restrict__ values,
    float* __restrict__ out)
{
    const int row = blockIdx.x;
    const float* vr = values + (size_t)row * N_VALS;
    const int tid = threadIdx.x;

    // Entries 0..15 = codebook sorted ascending (stable: equal values keep
    // original-index order); entry 16 = +inf sentinel.
    __shared__ Entry arr[N_VALS + 1];

    if (tid < N_VALS) {
        const float vi = vr[tid];
        int rank = 0;
#pragma unroll
        for (int j = 0; j < N_VALS; ++j) {
            const float vj = vr[j];
            rank += (vj < vi || (vj == vi && j < tid)) ? 1 : 0;
        }
        arr[rank].v = vi;
        arr[rank].idx = tid;
        if (tid == 0) { arr[N_VALS].v = INFINITY; arr[N_VALS].idx = 0x7fffffff; }
    }
    __syncthreads();

    // Static pivots (loop-invariant LDS reads, hoisted once per thread).
    const float p4 = arr[4].v, p8 = arr[8].v, p12 = arr[12].v;
    const char* base = (const char*)arr;

    const f32x4* xr   = (const f32x4*)(x   + (size_t)row * N_COLS);
    f32x4*       outr = (f32x4*)      (out + (size_t)row * N_COLS);

    // 2048 cols = 512 float4; 256 threads -> 2 iterations, fully coalesced.
#pragma unroll
    for (int it = 0; it < 2; ++it) {
        const int j = tid + it * 256;
        const f32x4 xv = xr[j];

        f32x4 o;
#pragma unroll
        for (int e = 0; e < 4; ++e) {
            const float xe = xv[e];

            // Branchless binary search: posB/8 = largest t in [0,15] with
            // arr[t].v <= xe (pos stays 0 if xe < all values -- still correct:
            // candidates {arr[0], arr[1]} contain the true nearest).
            const bool b1 = (p8 <= xe);
            int posB = b1 ? 64 : 0;
            const float pv2 = b1 ? p12 : p4;
            posB += (pv2 <= xe) ? 32 : 0;
            posB += (*(const float*)(base + posB + 16) <= xe) ? 16 : 0;
            posB += (*(const float*)(base + posB + 8)  <= xe) ? 8  : 0;

            const Entry L = *(const Entry*)(base + posB);
            const Entry R = *(const Entry*)(base + posB + 8);

            // numpy-exact pick: smaller rounded square; tie -> lower ORIGINAL
            // index. Sentinel dR = inf is never chosen.
            const float tL = xe - L.v;
            const float tR = xe - R.v;
            const float dL = tL * tL;
            const float dR = tR * tR;
            const bool takeL = (dL < dR) | ((dL == dR) & (L.idx < R.idx));
            o[e] = takeL ? L.v : R.v;
        }
        outr[j] = o;
    }
}

extern "C" void kernel_launch(void* const* d_in, const int* in_sizes, int n_in,
                              void* d_out, int out_size, void* d_ws, size_t ws_size,
                              hipStream_t stream) {
    const float* x      = (const float*)d_in[0];
    const float* values = (const float*)d_in[1];
    float* out          = (float*)d_out;

    vq_rowcodebook_kernel<<<N_ROWS, 256, 0, stream>>>(x, values, out);
}